// Round 1
// baseline (1694.289 us; speedup 1.0000x reference)
//
#include <hip/hip_runtime.h>
#include <cstdint>
#include <cstddef>

#define NN 16
#define DD 2048
#define BB 4096

typedef _Float16 half8 __attribute__((ext_vector_type(8)));
typedef _Float16 half4 __attribute__((ext_vector_type(4)));
typedef float f32x4 __attribute__((ext_vector_type(4)));

__device__ __forceinline__ float fast_tanh(float x) {
  float ax = __builtin_fabsf(x);
  float e = __expf(-2.0f * ax);
  float t = (1.0f - e) / (1.0f + e);
  return x < 0.0f ? -t : t;
}

// W fp32 [i][k][n]  ->  Wh fp16 [i][n][k]   (transpose + downconvert)
__global__ __launch_bounds__(256) void wconv_kernel(const float* __restrict__ W,
                                                    _Float16* __restrict__ Wh) {
  __shared__ _Float16 tile[64][80];  // [n][k], row stride 160B (16B-aligned, non-pow2 banks)
  const int i = blockIdx.z;
  const int k0 = blockIdx.y * 64;
  const int n0 = blockIdx.x * 64;
  const float* Wi = W + (size_t)i * DD * DD;
  _Float16* Whi = Wh + (size_t)i * DD * DD;
  const int t = threadIdx.x;
  const int cr = t >> 4;        // 0..15
  const int cc = (t & 15) * 4;  // 0..60
#pragma unroll
  for (int p = 0; p < 4; ++p) {
    int r = p * 16 + cr;
    float4 v = *(const float4*)(Wi + (size_t)(k0 + r) * DD + n0 + cc);
    tile[cc + 0][r] = (_Float16)v.x;
    tile[cc + 1][r] = (_Float16)v.y;
    tile[cc + 2][r] = (_Float16)v.z;
    tile[cc + 3][r] = (_Float16)v.w;
  }
  __syncthreads();
  const int wr = t >> 3;       // 0..31
  const int wc = (t & 7) * 8;  // 0..56
#pragma unroll
  for (int p = 0; p < 2; ++p) {
    int n = p * 32 + wr;
    half8 v = *(const half8*)&tile[n][wc];
    *(half8*)(Whi + (size_t)(n0 + n) * DD + k0 + wc) = v;
  }
}

// x fp32 -> S0 fp16 (elementwise)
__global__ __launch_bounds__(256) void xconv_kernel(const float* __restrict__ x,
                                                    _Float16* __restrict__ s0) {
  size_t idx = (size_t)(blockIdx.x * 256 + threadIdx.x) * 4;
  float4 v = *(const float4*)(x + idx);
  half4 o;
  o.x = (_Float16)v.x; o.y = (_Float16)v.y; o.z = (_Float16)v.z; o.w = (_Float16)v.w;
  *(half4*)(s0 + idx) = o;
}

// One DAG node: out = tanh(S @ Wt^T + bias); fused epilogue writes Y (fp16 y_i),
// Snext (fp16 y_i + y_{i-1}) or, for the terminal node, fp32 Ofinal.
__global__ __launch_bounds__(256) void node_gemm(
    const _Float16* __restrict__ S,      // [BB][DD] fp16 pre-summed input
    const _Float16* __restrict__ Wt,     // [DD][DD] fp16, layout [n][k]
    const float* __restrict__ bias,      // [DD]
    _Float16* __restrict__ Y,            // [BB][DD] fp16 tanh output
    const _Float16* __restrict__ Yprev,  // may be null (node 0)
    _Float16* __restrict__ Snext,        // [BB][DD] fp16 next-node input
    float* __restrict__ Ofinal)          // non-null only for terminal node
{
  __shared__ _Float16 As[128 * 64];
  __shared__ _Float16 Bs[128 * 64];

  const int t = threadIdx.x;
  const int lane = t & 63;
  const int wave = t >> 6;
  const int n0 = blockIdx.x * 128;
  const int m0 = blockIdx.y * 128;
  const int wm = (wave & 1) * 64;
  const int wn = (wave >> 1) * 64;
  const int lrow = lane & 15;
  const int lq = lane >> 4;

  f32x4 acc[4][4];
#pragma unroll
  for (int i = 0; i < 4; ++i)
#pragma unroll
    for (int j = 0; j < 4; ++j) acc[i][j] = (f32x4)0.0f;

  // Staging: chunk c = r*256 + t covers 16B each; row = c>>3, k-offset = (c&7)*8.
  const int sro = t >> 3;        // 0..31 (row base, +32 per round)
  const int sko = (t & 7) * 8;   // 0..56
  const _Float16* ag = S + (size_t)(m0 + sro) * DD + sko;
  const _Float16* bg = Wt + (size_t)(n0 + sro) * DD + sko;
  _Float16* al = As + (size_t)t * 8;
  _Float16* bl = Bs + (size_t)t * 8;

  for (int k0 = 0; k0 < DD; k0 += 64) {
#pragma unroll
    for (int r = 0; r < 4; ++r) {
      __builtin_amdgcn_global_load_lds(
          (const __attribute__((address_space(1))) void*)(ag + (size_t)(r * 32) * DD + k0),
          (__attribute__((address_space(3))) void*)(al + r * 2048), 16, 0, 0);
      __builtin_amdgcn_global_load_lds(
          (const __attribute__((address_space(1))) void*)(bg + (size_t)(r * 32) * DD + k0),
          (__attribute__((address_space(3))) void*)(bl + r * 2048), 16, 0, 0);
    }
    __syncthreads();
#pragma unroll
    for (int ks = 0; ks < 64; ks += 32) {
      half8 a[4], b[4];
#pragma unroll
      for (int mt = 0; mt < 4; ++mt)
        a[mt] = *(const half8*)(As + (wm + mt * 16 + lrow) * 64 + ks + lq * 8);
#pragma unroll
      for (int nt = 0; nt < 4; ++nt)
        b[nt] = *(const half8*)(Bs + (wn + nt * 16 + lrow) * 64 + ks + lq * 8);
#pragma unroll
      for (int mt = 0; mt < 4; ++mt)
#pragma unroll
        for (int nt = 0; nt < 4; ++nt)
          acc[mt][nt] =
              __builtin_amdgcn_mfma_f32_16x16x32_f16(a[mt], b[nt], acc[mt][nt], 0, 0, 0);
    }
    __syncthreads();
  }

  // Epilogue: C/D layout col = lane&15, row = (lane>>4)*4 + reg
#pragma unroll
  for (int nt = 0; nt < 4; ++nt) {
    const int col = n0 + wn + nt * 16 + lrow;
    const float bv = bias[col];
#pragma unroll
    for (int mt = 0; mt < 4; ++mt) {
      const int rowb = m0 + wm + mt * 16 + lq * 4;
#pragma unroll
      for (int r = 0; r < 4; ++r) {
        const size_t off = (size_t)(rowb + r) * DD + col;
        float y = fast_tanh(acc[mt][nt][r] + bv);
        if (Ofinal) {
          Ofinal[off] = y;
        } else {
          Y[off] = (_Float16)y;
          float s = y;
          if (Yprev) s += (float)Yprev[off];
          Snext[off] = (_Float16)s;
        }
      }
    }
  }
}

extern "C" void kernel_launch(void* const* d_in, const int* in_sizes, int n_in,
                              void* d_out, int out_size, void* d_ws, size_t ws_size,
                              hipStream_t stream) {
  const float* x = (const float*)d_in[0];
  const float* W = (const float*)d_in[1];
  const float* b = (const float*)d_in[2];
  float* out = (float*)d_out;
  char* ws = (char*)d_ws;

  _Float16* Wh = (_Float16*)ws;  // 128 MB
  size_t wbytes = (size_t)NN * DD * DD * sizeof(_Float16);
  _Float16* S0 = (_Float16*)(ws + wbytes);  // 16 MB each below
  _Float16* S1 = S0 + (size_t)BB * DD;
  _Float16* Y0 = S1 + (size_t)BB * DD;
  _Float16* Y1 = Y0 + (size_t)BB * DD;

  wconv_kernel<<<dim3(DD / 64, DD / 64, NN), dim3(256), 0, stream>>>(W, Wh);
  xconv_kernel<<<dim3((BB * DD) / 1024), dim3(256), 0, stream>>>(x, S0);

  _Float16* Sb[2] = {S0, S1};
  _Float16* Yb[2] = {Y0, Y1};
  dim3 ggrid(DD / 128, BB / 128);  // (16 n-tiles, 32 m-tiles)
  for (int i = 0; i < NN; ++i) {
    const _Float16* Sin = Sb[i & 1];
    _Float16* Sout = Sb[(i + 1) & 1];
    _Float16* Yout = Yb[i & 1];
    const _Float16* Yp = (i >= 1) ? Yb[(i + 1) & 1] : nullptr;
    const bool last = (i == NN - 1);
    node_gemm<<<ggrid, dim3(256), 0, stream>>>(Sin, Wh + (size_t)i * DD * DD,
                                               b + (size_t)i * DD, Yout, Yp, Sout,
                                               last ? out : nullptr);
  }
  (void)in_sizes; (void)n_in; (void)out_size; (void)ws_size;
}

// Round 3
// 1288.430 us; speedup vs baseline: 1.3150x; 1.3150x over previous
//
#include <hip/hip_runtime.h>
#include <cstdint>
#include <cstddef>

#define NN 16
#define DD 2048
#define BB 4096

#define TM 64
#define TN 128
#define BK 64

typedef _Float16 half8 __attribute__((ext_vector_type(8)));
typedef _Float16 half4 __attribute__((ext_vector_type(4)));
typedef float f32x4 __attribute__((ext_vector_type(4)));

__device__ __forceinline__ float fast_tanh(float x) {
  float ax = __builtin_fabsf(x);
  float e = __expf(-2.0f * ax);
  float t = (1.0f - e) / (1.0f + e);
  return x < 0.0f ? -t : t;
}

// W fp32 [i][k][n]  ->  Wh fp16 [i][n][k]   (transpose + downconvert)
__global__ __launch_bounds__(256) void wconv_kernel(const float* __restrict__ W,
                                                    _Float16* __restrict__ Wh) {
  __shared__ _Float16 tile[64][80];
  const int i = blockIdx.z;
  const int k0 = blockIdx.y * 64;
  const int n0 = blockIdx.x * 64;
  const float* Wi = W + (size_t)i * DD * DD;
  _Float16* Whi = Wh + (size_t)i * DD * DD;
  const int t = threadIdx.x;
  const int cr = t >> 4;
  const int cc = (t & 15) * 4;
#pragma unroll
  for (int p = 0; p < 4; ++p) {
    int r = p * 16 + cr;
    float4 v = *(const float4*)(Wi + (size_t)(k0 + r) * DD + n0 + cc);
    tile[cc + 0][r] = (_Float16)v.x;
    tile[cc + 1][r] = (_Float16)v.y;
    tile[cc + 2][r] = (_Float16)v.z;
    tile[cc + 3][r] = (_Float16)v.w;
  }
  __syncthreads();
  const int wr = t >> 3;
  const int wc = (t & 7) * 8;
#pragma unroll
  for (int p = 0; p < 2; ++p) {
    int n = p * 32 + wr;
    half8 v = *(const half8*)&tile[n][wc];
    *(half8*)(Whi + (size_t)(n0 + n) * DD + k0 + wc) = v;
  }
}

// x fp32 -> S0 fp16 (elementwise)
__global__ __launch_bounds__(256) void xconv_kernel(const float* __restrict__ x,
                                                    _Float16* __restrict__ s0) {
  size_t idx = (size_t)(blockIdx.x * 256 + threadIdx.x) * 4;
  float4 v = *(const float4*)(x + idx);
  half4 o;
  o.x = (_Float16)v.x; o.y = (_Float16)v.y; o.z = (_Float16)v.z; o.w = (_Float16)v.w;
  *(half4*)(s0 + idx) = o;
}

// One DAG node: out = tanh(S @ Wt^T + bias).
// 64m x 128n tile, BK=64, double-buffered LDS (one barrier/iter),
// XOR k-chunk swizzle for conflict-free ds_read_b128, LDS-transposed epilogue.
__global__ __launch_bounds__(256, 3) void node_gemm(
    const _Float16* __restrict__ S,      // [BB][DD] fp16 pre-summed input
    const _Float16* __restrict__ Wt,     // [DD][DD] fp16, layout [n][k]
    const float* __restrict__ bias,      // [DD]
    _Float16* __restrict__ Y,            // [BB][DD] fp16 tanh output
    const _Float16* __restrict__ Yprev,  // may be null (node 0)
    _Float16* __restrict__ Snext,        // [BB][DD] fp16 next-node input
    float* __restrict__ Ofinal)          // non-null only for terminal node
{
  // smem: As[2] (2*4096 halves) + Bs[2] (2*8192 halves) = 48 KB
  __shared__ _Float16 smem[2 * TM * BK + 2 * TN * BK];

  const int t = threadIdx.x;
  const int lane = t & 63;
  const int wave = t >> 6;
  const int n0 = blockIdx.x * TN;
  const int m0 = blockIdx.y * TM;
  const int wm = (wave & 1) * 32;   // wave tile: 32m x 64n
  const int wn = (wave >> 1) * 64;
  const int lrow = lane & 15;
  const int lq = lane >> 4;

  f32x4 acc[2][4];
#pragma unroll
  for (int i = 0; i < 2; ++i)
#pragma unroll
    for (int j = 0; j < 4; ++j) acc[i][j] = (f32x4)0.0f;

  // Staging: thread t covers LDS chunk (row = t>>3 [+32/round], chunk c = t&7).
  // XOR swizzle: LDS[row][c*8..] holds global k = (c ^ (row&7))*8 ..
  const int srow = t >> 3;
  const int ska = ((t & 7) ^ (srow & 7)) * 8;  // (row+32)&7 == row&7, so same all rounds
  const _Float16* ag = S + (size_t)(m0 + srow) * DD + ska;
  const _Float16* bg = Wt + (size_t)(n0 + srow) * DD + ska;

  auto stage = [&](int p, int k0) {
    const _Float16* a = ag + k0;
    const _Float16* b = bg + k0;
    _Float16* al = smem + p * (TM * BK) + t * 8;
    _Float16* bl = smem + 2 * (TM * BK) + p * (TN * BK) + t * 8;
    __builtin_amdgcn_global_load_lds(
        (const __attribute__((address_space(1))) void*)a,
        (__attribute__((address_space(3))) void*)al, 16, 0, 0);
    __builtin_amdgcn_global_load_lds(
        (const __attribute__((address_space(1))) void*)(a + 32 * DD),
        (__attribute__((address_space(3))) void*)(al + 2048), 16, 0, 0);
#pragma unroll
    for (int r = 0; r < 4; ++r)
      __builtin_amdgcn_global_load_lds(
          (const __attribute__((address_space(1))) void*)(b + (size_t)(r * 32) * DD),
          (__attribute__((address_space(3))) void*)(bl + r * 2048), 16, 0, 0);
  };

  stage(0, 0);

  for (int i = 0; i < DD / BK; ++i) {
    __syncthreads();  // publishes buf i&1 (loads issued last iter had full compute to land)
    if (i < DD / BK - 1) stage((i + 1) & 1, (i + 1) * BK);
    const _Float16* Ap = smem + (i & 1) * (TM * BK);
    const _Float16* Bp = smem + 2 * (TM * BK) + (i & 1) * (TN * BK);
#pragma unroll
    for (int ks = 0; ks < BK; ks += 32) {
      // chunk index after swizzle: same for A and B since (row&7)==(lrow&7)
      const int cx = (((ks >> 3) + lq) ^ (lrow & 7)) * 8;
      half8 a[2], b[4];
#pragma unroll
      for (int mt = 0; mt < 2; ++mt)
        a[mt] = *(const half8*)(Ap + (wm + mt * 16 + lrow) * BK + cx);
#pragma unroll
      for (int nt = 0; nt < 4; ++nt)
        b[nt] = *(const half8*)(Bp + (wn + nt * 16 + lrow) * BK + cx);
#pragma unroll
      for (int mt = 0; mt < 2; ++mt)
#pragma unroll
        for (int nt = 0; nt < 4; ++nt)
          acc[mt][nt] =
              __builtin_amdgcn_mfma_f32_16x16x32_f16(a[mt], b[nt], acc[mt][nt], 0, 0, 0);
    }
  }

  // Epilogue: acc -> LDS (fp16, [64][128]) -> coalesced global stores.
  __syncthreads();
  _Float16* CT = smem;  // 8192 halves = 16 KB, reuse As region
  float bv[4];
#pragma unroll
  for (int nt = 0; nt < 4; ++nt) bv[nt] = bias[n0 + wn + nt * 16 + lrow];
#pragma unroll
  for (int mt = 0; mt < 2; ++mt)
#pragma unroll
    for (int nt = 0; nt < 4; ++nt)
#pragma unroll
      for (int r = 0; r < 4; ++r) {
        int row = wm + mt * 16 + lq * 4 + r;
        int col = wn + nt * 16 + lrow;
        CT[row * TN + col] = (_Float16)fast_tanh(acc[mt][nt][r] + bv[nt]);
      }
  __syncthreads();

#pragma unroll
  for (int pp = 0; pp < 4; ++pp) {
    int idx = pp * 2048 + t * 8;
    int row = idx >> 7;
    int col = idx & 127;
    size_t off = (size_t)(m0 + row) * DD + n0 + col;
    half8 y = *(const half8*)&CT[idx];
    if (Ofinal) {
      float4 f0 = {(float)y[0], (float)y[1], (float)y[2], (float)y[3]};
      float4 f1 = {(float)y[4], (float)y[5], (float)y[6], (float)y[7]};
      *(float4*)(Ofinal + off) = f0;
      *(float4*)(Ofinal + off + 4) = f1;
    } else {
      *(half8*)(Y + off) = y;
      half8 s = y;
      if (Yprev) s = s + *(const half8*)(Yprev + off);
      *(half8*)(Snext + off) = s;
    }
  }
}

extern "C" void kernel_launch(void* const* d_in, const int* in_sizes, int n_in,
                              void* d_out, int out_size, void* d_ws, size_t ws_size,
                              hipStream_t stream) {
  const float* x = (const float*)d_in[0];
  const float* W = (const float*)d_in[1];
  const float* b = (const float*)d_in[2];
  float* out = (float*)d_out;
  char* ws = (char*)d_ws;

  _Float16* Wh = (_Float16*)ws;  // 128 MB
  size_t wbytes = (size_t)NN * DD * DD * sizeof(_Float16);
  _Float16* S0 = (_Float16*)(ws + wbytes);
  _Float16* S1 = S0 + (size_t)BB * DD;
  _Float16* Y0 = S1 + (size_t)BB * DD;
  _Float16* Y1 = Y0 + (size_t)BB * DD;

  wconv_kernel<<<dim3(DD / 64, DD / 64, NN), dim3(256), 0, stream>>>(W, Wh);
  xconv_kernel<<<dim3((BB * DD) / 1024), dim3(256), 0, stream>>>(x, S0);

  _Float16* Sb[2] = {S0, S1};
  _Float16* Yb[2] = {Y0, Y1};
  dim3 ggrid(DD / TN, BB / TM);  // 16 x 64 = 1024 blocks
  for (int i = 0; i < NN; ++i) {
    const _Float16* Sin = Sb[i & 1];
    _Float16* Sout = Sb[(i + 1) & 1];
    _Float16* Yout = Yb[i & 1];
    const _Float16* Yp = (i >= 1) ? Yb[(i + 1) & 1] : nullptr;
    const bool last = (i == NN - 1);
    node_gemm<<<ggrid, dim3(256), 0, stream>>>(Sin, Wh + (size_t)i * DD * DD,
                                               b + (size_t)i * DD, Yout, Yp, Sout,
                                               last ? out : nullptr);
  }
  (void)in_sizes; (void)n_in; (void)out_size; (void)ws_size;
}

// Round 4
// 1112.789 us; speedup vs baseline: 1.5226x; 1.1578x over previous
//
#include <hip/hip_runtime.h>
#include <cstdint>
#include <cstddef>

#define NN 16
#define DD 2048
#define BB 4096

#define TM 128
#define TN 128
#define BK 64

typedef _Float16 half8 __attribute__((ext_vector_type(8)));
typedef _Float16 half4 __attribute__((ext_vector_type(4)));
typedef float f32x4 __attribute__((ext_vector_type(4)));

__device__ __forceinline__ float fast_tanh(float x) {
  float ax = __builtin_fabsf(x);
  float e = __expf(-2.0f * ax);
  float t = (1.0f - e) / (1.0f + e);
  return x < 0.0f ? -t : t;
}

// W fp32 [i][k][n]  ->  Wh fp16 [i][n][k]   (transpose + downconvert)
__global__ __launch_bounds__(256) void wconv_kernel(const float* __restrict__ W,
                                                    _Float16* __restrict__ Wh) {
  __shared__ _Float16 tile[64][80];
  const int i = blockIdx.z;
  const int k0 = blockIdx.y * 64;
  const int n0 = blockIdx.x * 64;
  const float* Wi = W + (size_t)i * DD * DD;
  _Float16* Whi = Wh + (size_t)i * DD * DD;
  const int t = threadIdx.x;
  const int cr = t >> 4;
  const int cc = (t & 15) * 4;
#pragma unroll
  for (int p = 0; p < 4; ++p) {
    int r = p * 16 + cr;
    float4 v = *(const float4*)(Wi + (size_t)(k0 + r) * DD + n0 + cc);
    tile[cc + 0][r] = (_Float16)v.x;
    tile[cc + 1][r] = (_Float16)v.y;
    tile[cc + 2][r] = (_Float16)v.z;
    tile[cc + 3][r] = (_Float16)v.w;
  }
  __syncthreads();
  const int wr = t >> 3;
  const int wc = (t & 7) * 8;
#pragma unroll
  for (int p = 0; p < 2; ++p) {
    int n = p * 32 + wr;
    half8 v = *(const half8*)&tile[n][wc];
    *(half8*)(Whi + (size_t)(n0 + n) * DD + k0 + wc) = v;
  }
}

// x fp32 -> S0 fp16 (elementwise)
__global__ __launch_bounds__(256) void xconv_kernel(const float* __restrict__ x,
                                                    _Float16* __restrict__ s0) {
  size_t idx = (size_t)(blockIdx.x * 256 + threadIdx.x) * 4;
  float4 v = *(const float4*)(x + idx);
  half4 o;
  o.x = (_Float16)v.x; o.y = (_Float16)v.y; o.z = (_Float16)v.z; o.w = (_Float16)v.w;
  *(half4*)(s0 + idx) = o;
}

// One DAG node: out = tanh(S @ Wt^T + bias).
// 128x128 tile (4 waves x 64x64), BK=64, double-buffered LDS (one barrier/iter),
// XOR k-chunk swizzle, XCD-aware block mapping, LDS-transposed epilogue.
// 512 blocks @ 2 blocks/CU = exact full residency (no tail round).
__global__ __launch_bounds__(256, 2) void node_gemm(
    const _Float16* __restrict__ S,      // [BB][DD] fp16 pre-summed input
    const _Float16* __restrict__ Wt,     // [DD][DD] fp16, layout [n][k]
    const float* __restrict__ bias,      // [DD]
    _Float16* __restrict__ Y,            // [BB][DD] fp16 tanh output
    const _Float16* __restrict__ Yprev,  // may be null (node 0)
    _Float16* __restrict__ Snext,        // [BB][DD] fp16 next-node input
    float* __restrict__ Ofinal)          // non-null only for terminal node
{
  // smem: A dbuf 2*8192 + B dbuf 2*8192 halves = 64 KB
  __shared__ _Float16 smem[4 * TM * BK];

  const int t = threadIdx.x;
  const int lane = t & 63;
  const int wave = t >> 6;
  // XCD-aware mapping: g = n-tile, m = m-tile; XCD (bid%8) owns n-tiles {x,x+8}
  const int bid = blockIdx.x;
  const int n0 = (bid & 15) * TN;
  const int m0 = (bid >> 4) * TM;
  const int wm = (wave & 1) * 64;   // wave tile: 64m x 64n
  const int wn = (wave >> 1) * 64;
  const int lrow = lane & 15;
  const int lq = lane >> 4;

  f32x4 acc[4][4];
#pragma unroll
  for (int i = 0; i < 4; ++i)
#pragma unroll
    for (int j = 0; j < 4; ++j) acc[i][j] = (f32x4)0.0f;

  // Staging: thread t covers rows srow+32r (r=0..3), chunk c = t&7 (16B each).
  // XOR swizzle: LDS[row][c*8..] holds global k-chunk (c ^ (row&7)).
  const int srow = t >> 3;
  const int ska = ((t & 7) ^ (srow & 7)) * 8;  // (row+32k)&7 invariant
  const _Float16* ag = S + (size_t)(m0 + srow) * DD + ska;
  const _Float16* bg = Wt + (size_t)(n0 + srow) * DD + ska;

  auto stage = [&](int p, int k0) {
    const _Float16* a = ag + k0;
    const _Float16* b = bg + k0;
    _Float16* al = smem + p * (TM * BK) + t * 8;
    _Float16* bl = smem + 2 * (TM * BK) + p * (TN * BK) + t * 8;
#pragma unroll
    for (int r = 0; r < 4; ++r) {
      __builtin_amdgcn_global_load_lds(
          (const __attribute__((address_space(1))) void*)(a + (size_t)(r * 32) * DD),
          (__attribute__((address_space(3))) void*)(al + r * 2048), 16, 0, 0);
      __builtin_amdgcn_global_load_lds(
          (const __attribute__((address_space(1))) void*)(b + (size_t)(r * 32) * DD),
          (__attribute__((address_space(3))) void*)(bl + r * 2048), 16, 0, 0);
    }
  };

  stage(0, 0);

  for (int i = 0; i < DD / BK; ++i) {
    __syncthreads();  // publishes buf i&1 (its loads had a full compute phase to land)
    if (i < DD / BK - 1) stage((i + 1) & 1, (i + 1) * BK);
    const _Float16* Ap = smem + (i & 1) * (TM * BK);
    const _Float16* Bp = smem + 2 * (TM * BK) + (i & 1) * (TN * BK);
#pragma unroll
    for (int ks = 0; ks < BK; ks += 32) {
      const int cx = (((ks >> 3) + lq) ^ (lrow & 7)) * 8;
      half8 a[4], b[4];
#pragma unroll
      for (int mt = 0; mt < 4; ++mt)
        a[mt] = *(const half8*)(Ap + (wm + mt * 16 + lrow) * BK + cx);
#pragma unroll
      for (int nt = 0; nt < 4; ++nt)
        b[nt] = *(const half8*)(Bp + (wn + nt * 16 + lrow) * BK + cx);
#pragma unroll
      for (int mt = 0; mt < 4; ++mt)
#pragma unroll
        for (int nt = 0; nt < 4; ++nt)
          acc[mt][nt] =
              __builtin_amdgcn_mfma_f32_16x16x32_f16(a[mt], b[nt], acc[mt][nt], 0, 0, 0);
    }
  }

  // Epilogue: acc -> LDS (fp16, [128][128]) -> coalesced global stores.
  __syncthreads();
  _Float16* CT = smem;  // 16384 halves = 32 KB, reuse A region
  float bv[4];
#pragma unroll
  for (int nt = 0; nt < 4; ++nt) bv[nt] = bias[n0 + wn + nt * 16 + lrow];
#pragma unroll
  for (int mt = 0; mt < 4; ++mt)
#pragma unroll
    for (int nt = 0; nt < 4; ++nt)
#pragma unroll
      for (int r = 0; r < 4; ++r) {
        int row = wm + mt * 16 + lq * 4 + r;
        int col = wn + nt * 16 + lrow;
        CT[row * TN + col] = (_Float16)fast_tanh(acc[mt][nt][r] + bv[nt]);
      }
  __syncthreads();

#pragma unroll
  for (int pp = 0; pp < 8; ++pp) {
    int idx = pp * 2048 + t * 8;
    int row = idx >> 7;
    int col = idx & 127;
    size_t off = (size_t)(m0 + row) * DD + n0 + col;
    half8 y = *(const half8*)&CT[idx];
    if (Ofinal) {
      float4 f0 = {(float)y[0], (float)y[1], (float)y[2], (float)y[3]};
      float4 f1 = {(float)y[4], (float)y[5], (float)y[6], (float)y[7]};
      *(float4*)(Ofinal + off) = f0;
      *(float4*)(Ofinal + off + 4) = f1;
    } else {
      *(half8*)(Y + off) = y;
      half8 s = y;
      if (Yprev) s = s + *(const half8*)(Yprev + off);
      *(half8*)(Snext + off) = s;
    }
  }
}

extern "C" void kernel_launch(void* const* d_in, const int* in_sizes, int n_in,
                              void* d_out, int out_size, void* d_ws, size_t ws_size,
                              hipStream_t stream) {
  const float* x = (const float*)d_in[0];
  const float* W = (const float*)d_in[1];
  const float* b = (const float*)d_in[2];
  float* out = (float*)d_out;
  char* ws = (char*)d_ws;

  _Float16* Wh = (_Float16*)ws;  // 128 MB
  size_t wbytes = (size_t)NN * DD * DD * sizeof(_Float16);
  _Float16* S0 = (_Float16*)(ws + wbytes);
  _Float16* S1 = S0 + (size_t)BB * DD;
  _Float16* Y0 = S1 + (size_t)BB * DD;
  _Float16* Y1 = Y0 + (size_t)BB * DD;

  wconv_kernel<<<dim3(DD / 64, DD / 64, NN), dim3(256), 0, stream>>>(W, Wh);
  xconv_kernel<<<dim3((BB * DD) / 1024), dim3(256), 0, stream>>>(x, S0);

  _Float16* Sb[2] = {S0, S1};
  _Float16* Yb[2] = {Y0, Y1};
  dim3 ggrid((DD / TN) * (BB / TM));  // 16 x 32 = 512 blocks = 2/CU exact
  for (int i = 0; i < NN; ++i) {
    const _Float16* Sin = Sb[i & 1];
    _Float16* Sout = Sb[(i + 1) & 1];
    _Float16* Yout = Yb[i & 1];
    const _Float16* Yp = (i >= 1) ? Yb[(i + 1) & 1] : nullptr;
    const bool last = (i == NN - 1);
    node_gemm<<<ggrid, dim3(256), 0, stream>>>(Sin, Wh + (size_t)i * DD * DD,
                                               b + (size_t)i * DD, Yout, Yp, Sout,
                                               last ? out : nullptr);
  }
  (void)in_sizes; (void)n_in; (void)out_size; (void)ws_size;
}